// Round 9
// baseline (101.194 us; speedup 1.0000x reference)
//
#include <hip/hip_runtime.h>
#include <math.h>

#define T_LEN 8192
#define NTRIALS 1024
#define TN ((size_t)T_LEN * NTRIALS)
#define KLEN 50
#define CHUNK 64
#define NCHUNK (T_LEN / CHUNK)   // 128 chunks/trial
#define FARW 256                 // unchecked f32 warmup
#define NEARW 256                // checked f64 warmup
#define WARM (FARW + NEARW)      // 512
#define PF 32                    // prefetch depth (rows)
#define BAND 1e-4f               // ambiguity band (thr32 err <= 3e-5, 3x margin)

// ---------------------------------------------------------------------------
// Kernel 1 (fused prep): one block per time-row j. Every thread redundantly
// computes basc_j (50-tap f64 conv, ~200cy, memory-bound kernel unaffected),
// then converts its 4 rand elems to f32 thresholds. Lane 0 writes basc/bascf;
// block 0 lane 0 writes dparams. thr err <= ~3e-5 abs; exact path in scan.
// ---------------------------------------------------------------------------
__global__ __launch_bounds__(256) void prep_fused_kernel(
    const float* __restrict__ t, const float* __restrict__ stim,
    const float* __restrict__ bias, const float* __restrict__ k_stim,
    const float* __restrict__ hist_w, const float* __restrict__ hist_tau,
    const float* __restrict__ rnd, double* __restrict__ dparams,
    double* __restrict__ basc, float* __restrict__ bascf,
    float* __restrict__ thr32) {
  const int j = blockIdx.x;
  const int tid = threadIdx.x;
  const double dt = (double)t[1] - (double)t[0];

  // redundant per-thread basc_j (f64)
  double acc = 0.0;
  if (j > 0) {
    int n = j - 1;
    int mmax = n < (KLEN - 1) ? n : (KLEN - 1);
    for (int m = 0; m <= mmax; ++m)
      acc += (double)k_stim[m] * (double)stim[n - m];
  }
  double b64 = (double)bias[0] + (j > 0 ? dt * acc : 0.0);
  float bf = (float)b64;

  if (tid == 0) {
    basc[j] = b64;
    bascf[j] = bf;
    if (j == 0) {
      dparams[0] = exp(-dt / (double)hist_tau[0]);
      dparams[1] = exp(-dt / (double)hist_tau[1]);
      dparams[2] = (double)hist_w[0];
      dparams[3] = (double)hist_w[1];
      dparams[4] = dt;
    }
  }

  const float dtf = (float)dt;
  size_t m = (size_t)j * NTRIALS + (size_t)tid * 4;
  float4 r4 = *reinterpret_cast<const float4*>(rnd + m);
  float4 o;
  o.x = logf(-log1pf(-r4.x) / dtf) - bf;
  o.y = logf(-log1pf(-r4.y) / dtf) - bf;
  o.z = logf(-log1pf(-r4.z) / dtf) - bf;
  o.w = logf(-log1pf(-r4.w) / dtf) - bf;
  *reinterpret_cast<float4*>(thr32 + m) = o;
}

// Rare exact re-decision (band hit ~2e-5/lane-step): f64 ground truth.
__device__ __noinline__ bool decide64(const float* __restrict__ rnd,
                                      const double* __restrict__ basc,
                                      double dt, int j, int i, double h) {
  double r = (double)rnd[(size_t)j * NTRIALS + i];
  double t = log(-log1p(-r) / dt) - basc[j];
  return h > t;
}

// ---------------------------------------------------------------------------
// Kernel 2: speculative chunk-parallel scan. 2048 blocks x 1 wave = 8/CU =
// 2 waves/SIMD (the R4-measured occupancy where cy/step halves vs 1w/SIMD).
// blockIdx = c*16 + tb (tb in low bits): XCD = tb%8, per-XCD thr footprint
// 2 trial-groups x 2 MB = 4 MB ~ L2, so the 9x warmup re-read is L2-hit.
// Phases: FAR (<=256 steps, f32 state, unchecked), NEAR (<=256, f64 state,
// band-checked exact), OUT (64, checked + stores).
// ---------------------------------------------------------------------------
__global__ __launch_bounds__(64, 1) void spec_scan3_kernel(
    const float* __restrict__ thr, const float* __restrict__ rnd,
    const double* __restrict__ basc, const float* __restrict__ bascf,
    const double* __restrict__ dparams, float* __restrict__ out) {
  const int tid = threadIdx.x;
  const int tb  = blockIdx.x & 15;   // trial group (low bits -> XCD binding)
  const int c   = blockIdx.x >> 4;   // chunk 0..127
  const int i   = tb * 64 + tid;
  const double d0 = dparams[0], d1 = dparams[1];
  const double w0 = dparams[2], w1 = dparams[3];
  const double dt = dparams[4];
  const float d0f = (float)d0, d1f = (float)d1;
  const float w0f = (float)w0, w1f = (float)w1;

  const int jstart = c * CHUNK;
  const int nw    = jstart < WARM ? jstart : WARM;
  const int jw    = jstart - nw;
  const int nearn = nw < NEARW ? nw : NEARW;   // multiples of 64
  const int farn  = nw - nearn;                // multiples of 64
  const int j1    = jw + farn;

  const float* __restrict__ p = thr + i;  // column i, row stride NTRIALS
  float bufA[PF], bufB[PF];
#pragma unroll
  for (int k = 0; k < PF; ++k) bufA[k] = p[(size_t)(jw + k) * NTRIALS];
  __builtin_amdgcn_sched_barrier(0);

  // ---------------- FAR: f32 state, unchecked decisions ----------------
  float a0 = 0.0f, a1 = 0.0f;
  for (int q = 0; q < farn; q += 2 * PF) {
    const int j0 = jw + q;
#pragma unroll
    for (int k = 0; k < PF; ++k) bufB[k] = p[(size_t)(j0 + PF + k) * NTRIALS];
    __builtin_amdgcn_sched_barrier(0);
#pragma unroll
    for (int k = 0; k < PF; ++k) {
      float h = a0 + a1;
      bool s = h > bufA[k];
      a0 = fmaf(d0f, a0, s ? w0f : 0.0f);
      a1 = fmaf(d1f, a1, s ? w1f : 0.0f);
    }
    __builtin_amdgcn_sched_barrier(0);
#pragma unroll
    for (int k = 0; k < PF; ++k) bufA[k] = p[(size_t)(j0 + 2 * PF + k) * NTRIALS];
    __builtin_amdgcn_sched_barrier(0);
#pragma unroll
    for (int k = 0; k < PF; ++k) {
      float h = a0 + a1;
      bool s = h > bufB[k];
      a0 = fmaf(d0f, a0, s ? w0f : 0.0f);
      a1 = fmaf(d1f, a1, s ? w1f : 0.0f);
    }
    __builtin_amdgcn_sched_barrier(0);
  }

  // ---------------- NEAR: f64 state, band-checked exact ----------------
  double s0 = (double)a0, s1 = (double)a1;
  for (int q = 0; q < nearn; q += 2 * PF) {
    const int j0 = j1 + q;
#pragma unroll
    for (int k = 0; k < PF; ++k) bufB[k] = p[(size_t)(j0 + PF + k) * NTRIALS];
    __builtin_amdgcn_sched_barrier(0);
#pragma unroll
    for (int k = 0; k < PF; ++k) {
      double h = s0 + s1;
      float d = (float)h - bufA[k];
      bool s = d > 0.0f;
      if (__builtin_expect(fabsf(d) < BAND, 0))
        s = decide64(rnd, basc, dt, j0 + k, i, h);
      s0 = fma(d0, s0, s ? w0 : 0.0);
      s1 = fma(d1, s1, s ? w1 : 0.0);
    }
    __builtin_amdgcn_sched_barrier(0);
#pragma unroll
    for (int k = 0; k < PF; ++k) bufA[k] = p[(size_t)(j0 + 2 * PF + k) * NTRIALS];
    __builtin_amdgcn_sched_barrier(0);
#pragma unroll
    for (int k = 0; k < PF; ++k) {
      double h = s0 + s1;
      float d = (float)h - bufB[k];
      bool s = d > 0.0f;
      if (__builtin_expect(fabsf(d) < BAND, 0))
        s = decide64(rnd, basc, dt, j0 + PF + k, i, h);
      s0 = fma(d0, s0, s ? w0 : 0.0);
      s1 = fma(d1, s1, s ? w1 : 0.0);
    }
    __builtin_amdgcn_sched_barrier(0);
  }

  // ---------------- OUT: 64 checked steps + stores ----------------
  float* __restrict__ po_ll = out + (size_t)jstart * NTRIALS + i;
  float* __restrict__ po_mk = po_ll + TN;
#pragma unroll
  for (int k = 0; k < PF; ++k) bufB[k] = p[(size_t)(jstart + PF + k) * NTRIALS];
  __builtin_amdgcn_sched_barrier(0);
#pragma unroll
  for (int k = 0; k < PF; ++k) {
    double h = s0 + s1;
    float d = (float)h - bufA[k];
    bool s = d > 0.0f;
    if (__builtin_expect(fabsf(d) < BAND, 0))
      s = decide64(rnd, basc, dt, jstart + k, i, h);
    po_ll[(size_t)k * NTRIALS] = (float)h + bascf[jstart + k];
    po_mk[(size_t)k * NTRIALS] = s ? 1.0f : 0.0f;
    s0 = fma(d0, s0, s ? w0 : 0.0);
    s1 = fma(d1, s1, s ? w1 : 0.0);
  }
  __builtin_amdgcn_sched_barrier(0);
#pragma unroll
  for (int k = 0; k < PF; ++k) {
    double h = s0 + s1;
    float d = (float)h - bufB[k];
    bool s = d > 0.0f;
    if (__builtin_expect(fabsf(d) < BAND, 0))
      s = decide64(rnd, basc, dt, jstart + PF + k, i, h);
    po_ll[(size_t)(PF + k) * NTRIALS] = (float)h + bascf[jstart + PF + k];
    po_mk[(size_t)(PF + k) * NTRIALS] = s ? 1.0f : 0.0f;
    s0 = fma(d0, s0, s ? w0 : 0.0);
    s1 = fma(d1, s1, s ? w1 : 0.0);
  }
}

// Fallback (small ws): fully inline serial scan, correct but slow.
__global__ __launch_bounds__(64, 1) void glm_scan_inline_kernel(
    const float* __restrict__ rnd, const float* __restrict__ t,
    const float* __restrict__ stim, const float* __restrict__ bias,
    const float* __restrict__ k_stim, const float* __restrict__ hist_w,
    const float* __restrict__ hist_tau, float* __restrict__ out) {
  const int i = blockIdx.x * 64 + threadIdx.x;
  const double dt = (double)t[1] - (double)t[0];
  const double d0 = exp(-dt / (double)hist_tau[0]);
  const double d1 = exp(-dt / (double)hist_tau[1]);
  const double w0 = (double)hist_w[0], w1 = (double)hist_w[1];
  double s0 = 0.0, s1 = 0.0;
  float* __restrict__ out_ll = out;
  float* __restrict__ out_mk = out + TN;
  for (int j = 0; j < T_LEN; ++j) {
    double acc = 0.0;
    if (j > 0) {
      int n = j - 1;
      int mmax = n < (KLEN - 1) ? n : (KLEN - 1);
      for (int m = 0; m <= mmax; ++m)
        acc += (double)k_stim[m] * (double)stim[n - m];
    }
    double b = (double)bias[0] + dt * acc;
    double r = (double)rnd[(size_t)j * NTRIALS + i];
    double th = log(-log1p(-r) / dt) - b;
    double hist = s0 + s1;
    bool spk = hist > th;
    out_ll[(size_t)j * NTRIALS + i] = (float)(b + hist);
    out_mk[(size_t)j * NTRIALS + i] = spk ? 1.0f : 0.0f;
    s0 = fma(d0, s0, spk ? w0 : 0.0);
    s1 = fma(d1, s1, spk ? w1 : 0.0);
  }
}

extern "C" void kernel_launch(void* const* d_in, const int* in_sizes, int n_in,
                              void* d_out, int out_size, void* d_ws, size_t ws_size,
                              hipStream_t stream) {
  const float* t        = (const float*)d_in[0];
  const float* stim     = (const float*)d_in[1];
  const float* rnd      = (const float*)d_in[2];
  const float* bias     = (const float*)d_in[3];
  const float* k_stim   = (const float*)d_in[4];
  const float* hist_w   = (const float*)d_in[5];
  const float* hist_tau = (const float*)d_in[6];
  float* out = (float*)d_out;

  char* ws = (char*)d_ws;
  const size_t off_bascf = 64;
  const size_t off_basc  = off_bascf + (size_t)T_LEN * 4;
  const size_t off_thr   = off_basc + (size_t)T_LEN * 8;
  const size_t need_full = off_thr + TN * 4;   // f32 thresholds

  double* dparams = (double*)ws;
  float*  bascf   = (float*)(ws + off_bascf);
  double* basc    = (double*)(ws + off_basc);
  float*  thr32   = (float*)(ws + off_thr);

  if (ws_size >= need_full) {
    prep_fused_kernel<<<T_LEN, 256, 0, stream>>>(
        t, stim, bias, k_stim, hist_w, hist_tau, rnd, dparams, basc, bascf, thr32);
    spec_scan3_kernel<<<NCHUNK * 16, 64, 0, stream>>>(
        thr32, rnd, basc, bascf, dparams, out);
  } else {
    glm_scan_inline_kernel<<<NTRIALS / 64, 64, 0, stream>>>(
        rnd, t, stim, bias, k_stim, hist_w, hist_tau, out);
  }
}

// Round 10
// 99.459 us; speedup vs baseline: 1.0174x; 1.0174x over previous
//
#include <hip/hip_runtime.h>
#include <math.h>

#define T_LEN 8192
#define NTRIALS 1024
#define TN ((size_t)T_LEN * NTRIALS)
#define KLEN 50
#define CHUNK 64
#define NCHUNK (T_LEN / CHUNK)   // 128 chunks/trial
#define FARW 256                 // unchecked f32 warmup
#define NEARW 256                // checked f64 warmup
#define WARM (FARW + NEARW)      // 512
#define PF 32                    // prefetch depth (rows)
#define BAND 1e-4f               // ambiguity band (thr32 err <= 3e-5, 3x margin)

// ---------------------------------------------------------------------------
// Kernel 1 (fused prep): one block per time-row j. Every thread redundantly
// computes basc_j (50-tap f64 conv), then converts its 4 rand elems to f32
// thresholds. Lane 0 writes basc/bascf; block 0 lane 0 writes dparams.
// ---------------------------------------------------------------------------
__global__ __launch_bounds__(256) void prep_fused_kernel(
    const float* __restrict__ t, const float* __restrict__ stim,
    const float* __restrict__ bias, const float* __restrict__ k_stim,
    const float* __restrict__ hist_w, const float* __restrict__ hist_tau,
    const float* __restrict__ rnd, double* __restrict__ dparams,
    double* __restrict__ basc, float* __restrict__ bascf,
    float* __restrict__ thr32) {
  const int j = blockIdx.x;
  const int tid = threadIdx.x;
  const double dt = (double)t[1] - (double)t[0];

  double acc = 0.0;
  if (j > 0) {
    int n = j - 1;
    int mmax = n < (KLEN - 1) ? n : (KLEN - 1);
    for (int m = 0; m <= mmax; ++m)
      acc += (double)k_stim[m] * (double)stim[n - m];
  }
  double b64 = (double)bias[0] + (j > 0 ? dt * acc : 0.0);
  float bf = (float)b64;

  if (tid == 0) {
    basc[j] = b64;
    bascf[j] = bf;
    if (j == 0) {
      dparams[0] = exp(-dt / (double)hist_tau[0]);
      dparams[1] = exp(-dt / (double)hist_tau[1]);
      dparams[2] = (double)hist_w[0];
      dparams[3] = (double)hist_w[1];
      dparams[4] = dt;
    }
  }

  const float dtf = (float)dt;
  size_t m = (size_t)j * NTRIALS + (size_t)tid * 4;
  float4 r4 = *reinterpret_cast<const float4*>(rnd + m);
  float4 o;
  o.x = logf(-log1pf(-r4.x) / dtf) - bf;
  o.y = logf(-log1pf(-r4.y) / dtf) - bf;
  o.z = logf(-log1pf(-r4.z) / dtf) - bf;
  o.w = logf(-log1pf(-r4.w) / dtf) - bf;
  *reinterpret_cast<float4*>(thr32 + m) = o;
}

// Rare exact re-decision (band hit ~2e-5/lane-step): f64 ground truth.
__device__ __noinline__ bool decide64(const float* __restrict__ rnd,
                                      const double* __restrict__ basc,
                                      double dt, int j, int i, double h) {
  double r = (double)rnd[(size_t)j * NTRIALS + i];
  double t = log(-log1p(-r) / dt) - basc[j];
  return h > t;
}

// ---------------------------------------------------------------------------
// Kernel 2: speculative chunk-parallel scan. 2048 blocks x 1 wave = 8/CU =
// 2 waves/SIMD. blockIdx = c*16 + tb (tb low bits): XCD = tb%8, per-XCD thr
// footprint = 2 trial-groups x 2 MB = 4 MB = L2. R9 lesson: OUTPUT stores
// were evicting those slices (16.8 MB/XCD streamed through a 4 MB L2), so
// warmup re-reads went to HBM (FETCH 140 MB). Fix: ALL out stores are
// NON-TEMPORAL (bypass L2 allocation) -> thr stays L2-resident.
// Phases: FAR (<=256 steps, f32 state, unchecked), NEAR (<=256, f64 state,
// band-checked exact), OUT (64, checked + nt stores).
// ---------------------------------------------------------------------------
__global__ __launch_bounds__(64, 1) void spec_scan4_kernel(
    const float* __restrict__ thr, const float* __restrict__ rnd,
    const double* __restrict__ basc, const float* __restrict__ bascf,
    const double* __restrict__ dparams, float* __restrict__ out) {
  const int tid = threadIdx.x;
  const int tb  = blockIdx.x & 15;   // trial group (low bits -> XCD binding)
  const int c   = blockIdx.x >> 4;   // chunk 0..127
  const int i   = tb * 64 + tid;
  const double d0 = dparams[0], d1 = dparams[1];
  const double w0 = dparams[2], w1 = dparams[3];
  const double dt = dparams[4];
  const float d0f = (float)d0, d1f = (float)d1;
  const float w0f = (float)w0, w1f = (float)w1;

  const int jstart = c * CHUNK;
  const int nw    = jstart < WARM ? jstart : WARM;
  const int jw    = jstart - nw;
  const int nearn = nw < NEARW ? nw : NEARW;   // multiples of 64
  const int farn  = nw - nearn;                // multiples of 64
  const int j1    = jw + farn;

  const float* __restrict__ p = thr + i;  // column i, row stride NTRIALS
  float bufA[PF], bufB[PF];
#pragma unroll
  for (int k = 0; k < PF; ++k) bufA[k] = p[(size_t)(jw + k) * NTRIALS];
  __builtin_amdgcn_sched_barrier(0);

  // ---------------- FAR: f32 state, unchecked decisions ----------------
  float a0 = 0.0f, a1 = 0.0f;
  for (int q = 0; q < farn; q += 2 * PF) {
    const int j0 = jw + q;
#pragma unroll
    for (int k = 0; k < PF; ++k) bufB[k] = p[(size_t)(j0 + PF + k) * NTRIALS];
    __builtin_amdgcn_sched_barrier(0);
#pragma unroll
    for (int k = 0; k < PF; ++k) {
      float h = a0 + a1;
      bool s = h > bufA[k];
      a0 = fmaf(d0f, a0, s ? w0f : 0.0f);
      a1 = fmaf(d1f, a1, s ? w1f : 0.0f);
    }
    __builtin_amdgcn_sched_barrier(0);
#pragma unroll
    for (int k = 0; k < PF; ++k) bufA[k] = p[(size_t)(j0 + 2 * PF + k) * NTRIALS];
    __builtin_amdgcn_sched_barrier(0);
#pragma unroll
    for (int k = 0; k < PF; ++k) {
      float h = a0 + a1;
      bool s = h > bufB[k];
      a0 = fmaf(d0f, a0, s ? w0f : 0.0f);
      a1 = fmaf(d1f, a1, s ? w1f : 0.0f);
    }
    __builtin_amdgcn_sched_barrier(0);
  }

  // ---------------- NEAR: f64 state, band-checked exact ----------------
  double s0 = (double)a0, s1 = (double)a1;
  for (int q = 0; q < nearn; q += 2 * PF) {
    const int j0 = j1 + q;
#pragma unroll
    for (int k = 0; k < PF; ++k) bufB[k] = p[(size_t)(j0 + PF + k) * NTRIALS];
    __builtin_amdgcn_sched_barrier(0);
#pragma unroll
    for (int k = 0; k < PF; ++k) {
      double h = s0 + s1;
      float d = (float)h - bufA[k];
      bool s = d > 0.0f;
      if (__builtin_expect(fabsf(d) < BAND, 0))
        s = decide64(rnd, basc, dt, j0 + k, i, h);
      s0 = fma(d0, s0, s ? w0 : 0.0);
      s1 = fma(d1, s1, s ? w1 : 0.0);
    }
    __builtin_amdgcn_sched_barrier(0);
#pragma unroll
    for (int k = 0; k < PF; ++k) bufA[k] = p[(size_t)(j0 + 2 * PF + k) * NTRIALS];
    __builtin_amdgcn_sched_barrier(0);
#pragma unroll
    for (int k = 0; k < PF; ++k) {
      double h = s0 + s1;
      float d = (float)h - bufB[k];
      bool s = d > 0.0f;
      if (__builtin_expect(fabsf(d) < BAND, 0))
        s = decide64(rnd, basc, dt, j0 + PF + k, i, h);
      s0 = fma(d0, s0, s ? w0 : 0.0);
      s1 = fma(d1, s1, s ? w1 : 0.0);
    }
    __builtin_amdgcn_sched_barrier(0);
  }

  // ---------------- OUT: 64 checked steps + NON-TEMPORAL stores ----------------
  float* __restrict__ po_ll = out + (size_t)jstart * NTRIALS + i;
  float* __restrict__ po_mk = po_ll + TN;
#pragma unroll
  for (int k = 0; k < PF; ++k) bufB[k] = p[(size_t)(jstart + PF + k) * NTRIALS];
  __builtin_amdgcn_sched_barrier(0);
#pragma unroll
  for (int k = 0; k < PF; ++k) {
    double h = s0 + s1;
    float d = (float)h - bufA[k];
    bool s = d > 0.0f;
    if (__builtin_expect(fabsf(d) < BAND, 0))
      s = decide64(rnd, basc, dt, jstart + k, i, h);
    __builtin_nontemporal_store((float)h + bascf[jstart + k], po_ll + (size_t)k * NTRIALS);
    __builtin_nontemporal_store(s ? 1.0f : 0.0f, po_mk + (size_t)k * NTRIALS);
    s0 = fma(d0, s0, s ? w0 : 0.0);
    s1 = fma(d1, s1, s ? w1 : 0.0);
  }
  __builtin_amdgcn_sched_barrier(0);
#pragma unroll
  for (int k = 0; k < PF; ++k) {
    double h = s0 + s1;
    float d = (float)h - bufB[k];
    bool s = d > 0.0f;
    if (__builtin_expect(fabsf(d) < BAND, 0))
      s = decide64(rnd, basc, dt, jstart + PF + k, i, h);
    __builtin_nontemporal_store((float)h + bascf[jstart + PF + k], po_ll + (size_t)(PF + k) * NTRIALS);
    __builtin_nontemporal_store(s ? 1.0f : 0.0f, po_mk + (size_t)(PF + k) * NTRIALS);
    s0 = fma(d0, s0, s ? w0 : 0.0);
    s1 = fma(d1, s1, s ? w1 : 0.0);
  }
}

// Fallback (small ws): fully inline serial scan, correct but slow.
__global__ __launch_bounds__(64, 1) void glm_scan_inline_kernel(
    const float* __restrict__ rnd, const float* __restrict__ t,
    const float* __restrict__ stim, const float* __restrict__ bias,
    const float* __restrict__ k_stim, const float* __restrict__ hist_w,
    const float* __restrict__ hist_tau, float* __restrict__ out) {
  const int i = blockIdx.x * 64 + threadIdx.x;
  const double dt = (double)t[1] - (double)t[0];
  const double d0 = exp(-dt / (double)hist_tau[0]);
  const double d1 = exp(-dt / (double)hist_tau[1]);
  const double w0 = (double)hist_w[0], w1 = (double)hist_w[1];
  double s0 = 0.0, s1 = 0.0;
  float* __restrict__ out_ll = out;
  float* __restrict__ out_mk = out + TN;
  for (int j = 0; j < T_LEN; ++j) {
    double acc = 0.0;
    if (j > 0) {
      int n = j - 1;
      int mmax = n < (KLEN - 1) ? n : (KLEN - 1);
      for (int m = 0; m <= mmax; ++m)
        acc += (double)k_stim[m] * (double)stim[n - m];
    }
    double b = (double)bias[0] + dt * acc;
    double r = (double)rnd[(size_t)j * NTRIALS + i];
    double th = log(-log1p(-r) / dt) - b;
    double hist = s0 + s1;
    bool spk = hist > th;
    out_ll[(size_t)j * NTRIALS + i] = (float)(b + hist);
    out_mk[(size_t)j * NTRIALS + i] = spk ? 1.0f : 0.0f;
    s0 = fma(d0, s0, spk ? w0 : 0.0);
    s1 = fma(d1, s1, spk ? w1 : 0.0);
  }
}

extern "C" void kernel_launch(void* const* d_in, const int* in_sizes, int n_in,
                              void* d_out, int out_size, void* d_ws, size_t ws_size,
                              hipStream_t stream) {
  const float* t        = (const float*)d_in[0];
  const float* stim     = (const float*)d_in[1];
  const float* rnd      = (const float*)d_in[2];
  const float* bias     = (const float*)d_in[3];
  const float* k_stim   = (const float*)d_in[4];
  const float* hist_w   = (const float*)d_in[5];
  const float* hist_tau = (const float*)d_in[6];
  float* out = (float*)d_out;

  char* ws = (char*)d_ws;
  const size_t off_bascf = 64;
  const size_t off_basc  = off_bascf + (size_t)T_LEN * 4;
  const size_t off_thr   = off_basc + (size_t)T_LEN * 8;
  const size_t need_full = off_thr + TN * 4;   // f32 thresholds

  double* dparams = (double*)ws;
  float*  bascf   = (float*)(ws + off_bascf);
  double* basc    = (double*)(ws + off_basc);
  float*  thr32   = (float*)(ws + off_thr);

  if (ws_size >= need_full) {
    prep_fused_kernel<<<T_LEN, 256, 0, stream>>>(
        t, stim, bias, k_stim, hist_w, hist_tau, rnd, dparams, basc, bascf, thr32);
    spec_scan4_kernel<<<NCHUNK * 16, 64, 0, stream>>>(
        thr32, rnd, basc, bascf, dparams, out);
  } else {
    glm_scan_inline_kernel<<<NTRIALS / 64, 64, 0, stream>>>(
        rnd, t, stim, bias, k_stim, hist_w, hist_tau, out);
  }
}